// Round 1
// baseline (357.999 us; speedup 1.0000x reference)
//
#include <hip/hip_runtime.h>
#include <hip/hip_bf16.h>

#define N_ROWS 8192
#define N_HALF 4096
#define DIM    2048
#define INV_T  2.0f   // 1/TEMP, TEMP=0.5

typedef __attribute__((ext_vector_type(8))) short bf16x8;
typedef __attribute__((ext_vector_type(4))) float f32x4;

__device__ __forceinline__ float bf2f(short s) {
  return __uint_as_float(((unsigned int)(unsigned short)s) << 16);
}

// fp32 -> bf16 bits, round-to-nearest-even (finite inputs only)
__device__ __forceinline__ short f2bf(float x) {
  unsigned int u = __float_as_uint(x);
  u += 0x7fffu + ((u >> 16) & 1u);
  return (short)(u >> 16);
}

__device__ __forceinline__ void gload_lds16(const void* g, void* l) {
  __builtin_amdgcn_global_load_lds(
      (const __attribute__((address_space(1))) unsigned int*)g,
      (__attribute__((address_space(3))) unsigned int*)l, 16, 0, 0);
}

// ---------------------------------------------------------------------------
// Kernel 1: L2-normalize rows of x_i / x_j, write bf16 z (8192 x 2048)
// one block per row, 256 threads, 8 floats/thread
// ---------------------------------------------------------------------------
__global__ __launch_bounds__(256) void normalize_k(
    const float* __restrict__ xi, const float* __restrict__ xj,
    short* __restrict__ z)
{
  const int row = blockIdx.x;
  const int t   = threadIdx.x;
  const float* src = (row < N_HALF) ? (xi + (size_t)row * DIM)
                                    : (xj + (size_t)(row - N_HALF) * DIM);
  const float4* src4 = (const float4*)src;
  float4 v0 = src4[t * 2];
  float4 v1 = src4[t * 2 + 1];
  float ss = v0.x*v0.x + v0.y*v0.y + v0.z*v0.z + v0.w*v0.w
           + v1.x*v1.x + v1.y*v1.y + v1.z*v1.z + v1.w*v1.w;
  #pragma unroll
  for (int m = 1; m < 64; m <<= 1) ss += __shfl_xor(ss, m, 64);
  __shared__ float red[4];
  if ((t & 63) == 0) red[t >> 6] = ss;
  __syncthreads();
  float total = red[0] + red[1] + red[2] + red[3];
  float scale = 1.0f / fmaxf(sqrtf(total), 1e-12f);

  float f[8] = {v0.x, v0.y, v0.z, v0.w, v1.x, v1.y, v1.z, v1.w};
  bf16x8 pack;
  #pragma unroll
  for (int e = 0; e < 8; ++e) pack[e] = f2bf(f[e] * scale);
  *((bf16x8*)(z + (size_t)row * DIM) + t) = pack;
}

// ---------------------------------------------------------------------------
// Kernel 2: positives pos[i] = z_i . z_{i +/- N}, self[i] = z_i . z_i (bf16)
// one block per row
// ---------------------------------------------------------------------------
__global__ __launch_bounds__(256) void posself_k(
    const short* __restrict__ z, float* __restrict__ pos,
    float* __restrict__ selfd)
{
  const int i = blockIdx.x;
  const int j = (i < N_HALF) ? (i + N_HALF) : (i - N_HALF);
  const int t = threadIdx.x;
  const bf16x8 va = ((const bf16x8*)(z + (size_t)i * DIM))[t];
  const bf16x8 vb = ((const bf16x8*)(z + (size_t)j * DIM))[t];
  float sp = 0.f, ss = 0.f;
  #pragma unroll
  for (int e = 0; e < 8; ++e) {
    float fa = bf2f(va[e]), fb = bf2f(vb[e]);
    sp += fa * fb;
    ss += fa * fa;
  }
  #pragma unroll
  for (int m = 1; m < 64; m <<= 1) {
    sp += __shfl_xor(sp, m, 64);
    ss += __shfl_xor(ss, m, 64);
  }
  __shared__ float rp[4], rs[4];
  if ((t & 63) == 0) { rp[t >> 6] = sp; rs[t >> 6] = ss; }
  __syncthreads();
  if (t == 0) {
    pos[i]   = rp[0] + rp[1] + rp[2] + rp[3];
    selfd[i] = rs[0] + rs[1] + rs[2] + rs[3];
  }
}

// ---------------------------------------------------------------------------
// Kernel 3: fused sim = z z^T tile + exp(sim/T) row-sum into denom[8192]
// 128x128 tile / block, 4 waves (2x2), each wave 64x64 via 4x4 16x16x32 MFMA,
// BK=32, global_load_lds 16B staging (m97 structure).
// denom gets the FULL row sum (incl. diagonal term); subtracted later.
// ---------------------------------------------------------------------------
__global__ __launch_bounds__(256) void simexp_k(
    const short* __restrict__ z, float* __restrict__ denom)
{
  __shared__ short As[128 * 32];  // 8 KB
  __shared__ short Bs[128 * 32];  // 8 KB

  const int t    = threadIdx.x;
  const int wave = t >> 6, lane = t & 63;
  const int wr   = wave >> 1, wc = wave & 1;
  const int row0 = blockIdx.x * 128;
  const int col0 = blockIdx.y * 128;

  f32x4 acc[4][4] = {};

  const int lrow = t >> 2;          // 0..63
  const int lcol = (t & 3) * 8;     // 0,8,16,24
  const short* gA = z + (size_t)(row0 + lrow) * DIM + lcol;
  const short* gB = z + (size_t)(col0 + lrow) * DIM + lcol;
  char* ldsA = (char*)As + wave * 1024;  // wave-uniform LDS dest base
  char* ldsB = (char*)Bs + wave * 1024;

  for (int kt = 0; kt < DIM; kt += 32) {
    // stage A tile (128x32) and B tile (128x32): 2 calls each (4KB/call)
    gload_lds16(gA + kt,            ldsA);
    gload_lds16(gA + kt + 64 * DIM, ldsA + 4096);
    gload_lds16(gB + kt,            ldsB);
    gload_lds16(gB + kt + 64 * DIM, ldsB + 4096);
    __syncthreads();

    bf16x8 a[4], b[4];
    const bf16x8* Av = (const bf16x8*)As;
    const bf16x8* Bv = (const bf16x8*)Bs;
    #pragma unroll
    for (int m = 0; m < 4; ++m)
      a[m] = Av[(wr * 64 + m * 16 + (lane & 15)) * 4 + (lane >> 4)];
    #pragma unroll
    for (int n = 0; n < 4; ++n)
      b[n] = Bv[(wc * 64 + n * 16 + (lane & 15)) * 4 + (lane >> 4)];

    #pragma unroll
    for (int m = 0; m < 4; ++m)
      #pragma unroll
      for (int n = 0; n < 4; ++n)
        acc[m][n] = __builtin_amdgcn_mfma_f32_16x16x32_bf16(a[m], b[n],
                                                            acc[m][n], 0, 0, 0);
    __syncthreads();
  }

  // epilogue: v = exp(sim * 2); row-sum over this block's 128 cols.
  // C layout: col = lane&15, row = (lane>>4)*4 + reg
  #pragma unroll
  for (int m = 0; m < 4; ++m) {
    #pragma unroll
    for (int r = 0; r < 4; ++r) {
      float s = 0.f;
      #pragma unroll
      for (int n = 0; n < 4; ++n) s += __expf(acc[m][n][r] * INV_T);
      // sum over the 16 lanes of the column group -> 64 cols total
      s += __shfl_xor(s, 1, 64);
      s += __shfl_xor(s, 2, 64);
      s += __shfl_xor(s, 4, 64);
      s += __shfl_xor(s, 8, 64);
      if ((lane & 15) == 0) {
        int grow = row0 + wr * 64 + m * 16 + (lane >> 4) * 4 + r;
        atomicAdd(&denom[grow], s);
      }
    }
  }
}

// ---------------------------------------------------------------------------
// Kernel 4: loss = mean_i( log(denom_i - exp(self_i/T)) - pos_i/T )
// ---------------------------------------------------------------------------
__global__ __launch_bounds__(256) void loss_k(
    const float* __restrict__ denom, const float* __restrict__ pos,
    const float* __restrict__ selfd, float* __restrict__ out)
{
  const int t = threadIdx.x;
  float acc = 0.f;
  for (int i = t; i < N_ROWS; i += 256) {
    float d = denom[i] - __expf(selfd[i] * INV_T);
    acc += __logf(d) - pos[i] * INV_T;
  }
  #pragma unroll
  for (int m = 1; m < 64; m <<= 1) acc += __shfl_xor(acc, m, 64);
  __shared__ float red[4];
  if ((t & 63) == 0) red[t >> 6] = acc;
  __syncthreads();
  if (t == 0) out[0] = (red[0] + red[1] + red[2] + red[3]) / (float)N_ROWS;
}

// ---------------------------------------------------------------------------
extern "C" void kernel_launch(void* const* d_in, const int* in_sizes, int n_in,
                              void* d_out, int out_size, void* d_ws, size_t ws_size,
                              hipStream_t stream) {
  const float* xi = (const float*)d_in[0];
  const float* xj = (const float*)d_in[1];
  float* out = (float*)d_out;

  char*  ws    = (char*)d_ws;
  short* zb    = (short*)ws;                                   // 32 MiB bf16 z
  float* denom = (float*)(ws + (size_t)N_ROWS * DIM * 2);      // 8192 f32
  float* pos   = denom + N_ROWS;                               // 8192 f32
  float* selfd = pos + N_ROWS;                                 // 8192 f32

  hipMemsetAsync(denom, 0, N_ROWS * sizeof(float), stream);
  normalize_k<<<N_ROWS, 256, 0, stream>>>(xi, xj, zb);
  posself_k<<<N_ROWS, 256, 0, stream>>>(zb, pos, selfd);
  dim3 grid(N_ROWS / 128, N_ROWS / 128);
  simexp_k<<<grid, 256, 0, stream>>>(zb, denom);
  loss_k<<<1, 256, 0, stream>>>(denom, pos, selfd, out);
}

// Round 2
// 224.497 us; speedup vs baseline: 1.5947x; 1.5947x over previous
//
#include <hip/hip_runtime.h>
#include <hip/hip_bf16.h>

#define N_ROWS 8192
#define N_HALF 4096
#define DIM    2048
#define INV_T  2.0f   // 1/TEMP, TEMP=0.5
#define NBLK   64     // 8192/128
#define NPAIR  2080   // NBLK*(NBLK+1)/2

typedef __attribute__((ext_vector_type(8))) short bf16x8;
typedef __attribute__((ext_vector_type(4))) float f32x4;

__device__ __forceinline__ float bf2f(short s) {
  return __uint_as_float(((unsigned int)(unsigned short)s) << 16);
}

// fp32 -> bf16 bits, round-to-nearest-even (finite inputs only)
__device__ __forceinline__ short f2bf(float x) {
  unsigned int u = __float_as_uint(x);
  u += 0x7fffu + ((u >> 16) & 1u);
  return (short)(u >> 16);
}

__device__ __forceinline__ void gload_lds16(const void* g, void* l) {
  __builtin_amdgcn_global_load_lds(
      (const __attribute__((address_space(1))) unsigned int*)g,
      (__attribute__((address_space(3))) unsigned int*)l, 16, 0, 0);
}

// ---------------------------------------------------------------------------
// Kernel 1: L2-normalize rows of x_i / x_j, write bf16 z (8192 x 2048)
// ---------------------------------------------------------------------------
__global__ __launch_bounds__(256) void normalize_k(
    const float* __restrict__ xi, const float* __restrict__ xj,
    short* __restrict__ z)
{
  const int row = blockIdx.x;
  const int t   = threadIdx.x;
  const float* src = (row < N_HALF) ? (xi + (size_t)row * DIM)
                                    : (xj + (size_t)(row - N_HALF) * DIM);
  const float4* src4 = (const float4*)src;
  float4 v0 = src4[t * 2];
  float4 v1 = src4[t * 2 + 1];
  float ss = v0.x*v0.x + v0.y*v0.y + v0.z*v0.z + v0.w*v0.w
           + v1.x*v1.x + v1.y*v1.y + v1.z*v1.z + v1.w*v1.w;
  #pragma unroll
  for (int m = 1; m < 64; m <<= 1) ss += __shfl_xor(ss, m, 64);
  __shared__ float red[4];
  if ((t & 63) == 0) red[t >> 6] = ss;
  __syncthreads();
  float total = red[0] + red[1] + red[2] + red[3];
  float scale = 1.0f / fmaxf(sqrtf(total), 1e-12f);

  float f[8] = {v0.x, v0.y, v0.z, v0.w, v1.x, v1.y, v1.z, v1.w};
  bf16x8 pack;
  #pragma unroll
  for (int e = 0; e < 8; ++e) pack[e] = f2bf(f[e] * scale);
  *((bf16x8*)(z + (size_t)row * DIM) + t) = pack;
}

// ---------------------------------------------------------------------------
// Kernel 2: positives pos[i] = z_i . z_{i +/- N}, self[i] = z_i . z_i (bf16)
// ---------------------------------------------------------------------------
__global__ __launch_bounds__(256) void posself_k(
    const short* __restrict__ z, float* __restrict__ pos,
    float* __restrict__ selfd)
{
  const int i = blockIdx.x;
  const int j = (i < N_HALF) ? (i + N_HALF) : (i - N_HALF);
  const int t = threadIdx.x;
  const bf16x8 va = ((const bf16x8*)(z + (size_t)i * DIM))[t];
  const bf16x8 vb = ((const bf16x8*)(z + (size_t)j * DIM))[t];
  float sp = 0.f, ss = 0.f;
  #pragma unroll
  for (int e = 0; e < 8; ++e) {
    float fa = bf2f(va[e]), fb = bf2f(vb[e]);
    sp += fa * fb;
    ss += fa * fa;
  }
  #pragma unroll
  for (int m = 1; m < 64; m <<= 1) {
    sp += __shfl_xor(sp, m, 64);
    ss += __shfl_xor(ss, m, 64);
  }
  __shared__ float rp[4], rs[4];
  if ((t & 63) == 0) { rp[t >> 6] = sp; rs[t >> 6] = ss; }
  __syncthreads();
  if (t == 0) {
    pos[i]   = rp[0] + rp[1] + rp[2] + rp[3];
    selfd[i] = rs[0] + rs[1] + rs[2] + rs[3];
  }
}

// ---------------------------------------------------------------------------
// Kernel 3: symmetric fused sim-tile + exp row/col sums.
// Upper-triangular 128x128 block pairs only (2080 blocks): off-diagonal tile
// T = Z_bi Z_bj^T contributes row-sums of exp(T*2) to denom[bi rows] AND
// col-sums to denom[bj rows] (T^T contribution). Diagonal blocks: row-sums
// only (full 128x128 computed).
// ---------------------------------------------------------------------------
__global__ __launch_bounds__(256) void simexp_k(
    const short* __restrict__ z, float* __restrict__ denom)
{
  __shared__ short As[128 * 32];  // 8 KB
  __shared__ short Bs[128 * 32];  // 8 KB

  const int t    = threadIdx.x;
  const int wave = t >> 6, lane = t & 63;
  const int wr   = wave >> 1, wc = wave & 1;

  // triangular index -> (bi, bj), bi <= bj
  int rem = blockIdx.x, bi = 0;
  while (rem >= NBLK - bi) { rem -= NBLK - bi; ++bi; }
  const int bj   = bi + rem;
  const int row0 = bi * 128;
  const int col0 = bj * 128;

  f32x4 acc[4][4] = {};

  const int lrow = t >> 2;          // 0..63
  const int lcol = (t & 3) * 8;     // 0,8,16,24
  const short* gA = z + (size_t)(row0 + lrow) * DIM + lcol;
  const short* gB = z + (size_t)(col0 + lrow) * DIM + lcol;
  char* ldsA = (char*)As + wave * 1024;  // wave-uniform LDS dest base
  char* ldsB = (char*)Bs + wave * 1024;

  for (int kt = 0; kt < DIM; kt += 32) {
    gload_lds16(gA + kt,            ldsA);
    gload_lds16(gA + kt + 64 * DIM, ldsA + 4096);
    gload_lds16(gB + kt,            ldsB);
    gload_lds16(gB + kt + 64 * DIM, ldsB + 4096);
    __syncthreads();

    bf16x8 a[4], b[4];
    const bf16x8* Av = (const bf16x8*)As;
    const bf16x8* Bv = (const bf16x8*)Bs;
    #pragma unroll
    for (int m = 0; m < 4; ++m)
      a[m] = Av[(wr * 64 + m * 16 + (lane & 15)) * 4 + (lane >> 4)];
    #pragma unroll
    for (int n = 0; n < 4; ++n)
      b[n] = Bv[(wc * 64 + n * 16 + (lane & 15)) * 4 + (lane >> 4)];

    #pragma unroll
    for (int m = 0; m < 4; ++m)
      #pragma unroll
      for (int n = 0; n < 4; ++n)
        acc[m][n] = __builtin_amdgcn_mfma_f32_16x16x32_bf16(a[m], b[n],
                                                            acc[m][n], 0, 0, 0);
    __syncthreads();
  }

  // exp in place: acc[m][n][r] = exp(sim * 2)
  #pragma unroll
  for (int m = 0; m < 4; ++m)
    #pragma unroll
    for (int n = 0; n < 4; ++n)
      #pragma unroll
      for (int r = 0; r < 4; ++r)
        acc[m][n][r] = __expf(acc[m][n][r] * INV_T);

  // row sums: reduce over n-fragments + the 16-lane col group (lane&15)
  // C layout: col = lane&15, row = (lane>>4)*4 + reg
  #pragma unroll
  for (int m = 0; m < 4; ++m) {
    #pragma unroll
    for (int r = 0; r < 4; ++r) {
      float s = acc[m][0][r] + acc[m][1][r] + acc[m][2][r] + acc[m][3][r];
      s += __shfl_xor(s, 1, 64);
      s += __shfl_xor(s, 2, 64);
      s += __shfl_xor(s, 4, 64);
      s += __shfl_xor(s, 8, 64);
      if ((lane & 15) == 0) {
        int grow = row0 + wr * 64 + m * 16 + (lane >> 4) * 4 + r;
        atomicAdd(&denom[grow], s);
      }
    }
  }

  // col sums (transposed-tile contribution), off-diagonal blocks only:
  // reduce over m-fragments, regs, and the lane>>4 row-group (xor 16,32)
  if (bi != bj) {
    #pragma unroll
    for (int n = 0; n < 4; ++n) {
      float cs = 0.f;
      #pragma unroll
      for (int m = 0; m < 4; ++m)
        #pragma unroll
        for (int r = 0; r < 4; ++r)
          cs += acc[m][n][r];
      cs += __shfl_xor(cs, 16, 64);
      cs += __shfl_xor(cs, 32, 64);
      if ((lane >> 4) == 0) {
        int gcol = col0 + wc * 64 + n * 16 + (lane & 15);
        atomicAdd(&denom[gcol], cs);
      }
    }
  }
}

// ---------------------------------------------------------------------------
// Kernel 4: loss = mean_i( log(denom_i - exp(self_i/T)) - pos_i/T )
// ---------------------------------------------------------------------------
__global__ __launch_bounds__(256) void loss_k(
    const float* __restrict__ denom, const float* __restrict__ pos,
    const float* __restrict__ selfd, float* __restrict__ out)
{
  const int t = threadIdx.x;
  float acc = 0.f;
  for (int i = t; i < N_ROWS; i += 256) {
    float d = denom[i] - __expf(selfd[i] * INV_T);
    acc += __logf(d) - pos[i] * INV_T;
  }
  #pragma unroll
  for (int m = 1; m < 64; m <<= 1) acc += __shfl_xor(acc, m, 64);
  __shared__ float red[4];
  if ((t & 63) == 0) red[t >> 6] = acc;
  __syncthreads();
  if (t == 0) out[0] = (red[0] + red[1] + red[2] + red[3]) / (float)N_ROWS;
}

// ---------------------------------------------------------------------------
extern "C" void kernel_launch(void* const* d_in, const int* in_sizes, int n_in,
                              void* d_out, int out_size, void* d_ws, size_t ws_size,
                              hipStream_t stream) {
  const float* xi = (const float*)d_in[0];
  const float* xj = (const float*)d_in[1];
  float* out = (float*)d_out;

  char*  ws    = (char*)d_ws;
  short* zb    = (short*)ws;                                   // 32 MiB bf16 z
  float* denom = (float*)(ws + (size_t)N_ROWS * DIM * 2);      // 8192 f32
  float* pos   = denom + N_ROWS;                               // 8192 f32
  float* selfd = pos + N_ROWS;                                 // 8192 f32

  hipMemsetAsync(denom, 0, N_ROWS * sizeof(float), stream);
  normalize_k<<<N_ROWS, 256, 0, stream>>>(xi, xj, zb);
  posself_k<<<N_ROWS, 256, 0, stream>>>(zb, pos, selfd);
  simexp_k<<<NPAIR, 256, 0, stream>>>(zb, denom);
  loss_k<<<1, 256, 0, stream>>>(denom, pos, selfd, out);
}